// Round 1
// baseline (4613.321 us; speedup 1.0000x reference)
//
#include <hip/hip_runtime.h>
#include <math.h>

#define D      1024
#define NHEADS 16
#define HDIM   64
#define NL     2
#define FF     4096
#define NGRP   15
#define VOC    2048
#define TOPK   50
#define MAXS   16
#define NB     256

struct Params {
    const float* talker; const float* code0; const float* temp; const float* unis;
    const float* heads;  const float* embeds;
    const float* ln1; const float* ln2; const float* lnf;
    const float* wq; const float* wk; const float* wv; const float* wo;
    const float* w1; const float* w2;
    float* out; float* ws;
};

__device__ __forceinline__ float wave_reduce_sum(float v) {
#pragma unroll
    for (int m = 32; m >= 1; m >>= 1) v += __shfl_xor(v, m, 64);
    return v;
}

__device__ __forceinline__ float geluf(float y) {
    return 0.5f * y * (1.f + tanhf(0.7978845608028654f * (y + 0.044715f * y * y * y)));
}

// Monotonic-counter grid barrier. Safe because cnt never resets within a launch:
// barrier i complete when cnt >= i*NB. 180 barriers * 256 blocks << 2^32.
// atomicAdd is device-scope (sc1, coherent point) on gfx950; __threadfence emits
// buffer_wbl2/buffer_inv for cross-XCD release/acquire of the normal stores.
__device__ __forceinline__ void gsync(unsigned* cnt, unsigned target) {
    __syncthreads();
    if (threadIdx.x == 0) {
        __threadfence();                 // release: flush this XCD's dirty L2
        atomicAdd(cnt, 1u);
        while (__hip_atomic_load(cnt, __ATOMIC_RELAXED, __HIP_MEMORY_SCOPE_AGENT) < target)
            __builtin_amdgcn_s_sleep(1);
        __threadfence();                 // acquire: invalidate local caches
    }
    __syncthreads();
}

// 256-thread block helper: xn[] = rms(src)*w, red[] is 256-float scratch.
__device__ __forceinline__ void load_rms(const float* __restrict__ src,
                                         const float* __restrict__ w,
                                         float* xn, float* red) {
    int tid = threadIdx.x;
    float ss = 0.f;
    for (int i = tid; i < D; i += 256) { float v = src[i]; xn[i] = v; ss += v * v; }
    red[tid] = ss;
    __syncthreads();
    for (int s = 128; s > 0; s >>= 1) {
        if (tid < s) red[tid] += red[tid + s];
        __syncthreads();
    }
    float inv = rsqrtf(red[0] / (float)D + 1e-6f);
    for (int i = tid; i < D; i += 256) xn[i] = xn[i] * inv * w[i];
    __syncthreads();
}

// init: h = talker||code0, out tail = code0, zero qkv, zero barrier counter.
__global__ __launch_bounds__(256) void k_pre(const float* __restrict__ th,
                                             const float* __restrict__ c0,
                                             float* __restrict__ h,
                                             float* __restrict__ out,
                                             float* __restrict__ qkv,
                                             unsigned* __restrict__ bar) {
    int i = blockIdx.x * 256 + threadIdx.x;   // grid 8 x 256 = 2048
    if (i == 0) *bar = 0u;
    if (i < 1024) {
        h[i] = th[i];
        h[D + i] = c0[i];
        out[NGRP + i] = c0[i];
    }
    for (int j = i; j < 2 * 3 * D; j += 2048) qkv[j] = 0.f;
}

__global__ __launch_bounds__(256) void k_all(Params p) {
    __shared__ float xn[D];
    __shared__ float red[256];
    __shared__ float4 part[4][64];
    __shared__ float s_topv[TOPK];
    __shared__ int   s_topi[TOPK];
    __shared__ int   s_code;

    float* ws   = p.ws;
    float* h    = ws;            // 2*1024
    float* qkvb = ws + 2048;     // 2*3*1024
    float* ao   = ws + 8192;     // 2*1024
    float* kc   = ws + 10240;    // 2*16*1024
    float* vc   = ws + 43008;    // 2*16*1024
    float* ub   = ws + 75776;    // 2*4096
    float* lg   = ws + 83968;    // 2048
    unsigned* bar = (unsigned*)(ws + 86016);

    const int bid = blockIdx.x;
    const int tid = threadIdx.x;
    unsigned bt = 0;

    auto step = [&](int T, int basePos) {
        for (int l = 0; l < NL; ++l) {
            // ---------- QKV: tasks = 12 x 8 x T (identical split to k_qkv) ----------
            if (bid < 96 * T) {
                int x = bid % 12, y = (bid / 12) % 8, t = bid / 96;
                int m = x >> 2, ob = x & 3;
                load_rms(h + t * D, p.ln1 + l * D, xn, red);
                const float* W = ((m == 0) ? p.wq : (m == 1) ? p.wk : p.wv) + (long)l * D * D;
                int w = tid >> 6, lane = tid & 63;
                int obase = ob * 256;
                int kbase = (y * 4 + w) * 32;
                const float* Wp = W + (long)kbase * D + obase + lane * 4;
                float4 acc = {0.f, 0.f, 0.f, 0.f};
#pragma unroll 4
                for (int i = 0; i < 32; ++i) {
                    float xv = xn[kbase + i];
                    float4 wv4 = *(const float4*)(Wp + (long)i * D);
                    acc.x += xv * wv4.x; acc.y += xv * wv4.y;
                    acc.z += xv * wv4.z; acc.w += xv * wv4.w;
                }
                part[w][lane] = acc;
                __syncthreads();
                const float* pp = (const float*)part;
                float s = pp[tid] + pp[256 + tid] + pp[512 + tid] + pp[768 + tid];
                atomicAdd(&qkvb[t * 3 * D + m * D + obase + tid], s);
            }
            gsync(bar, bt += NB);

            // ---------- ATTN (+ zero ub): wave tasks = T x 16 ----------
            {
                for (int i = bid * 256 + tid; i < T * FF; i += NB * 256) ub[i] = 0.f;
                int wid = bid * 4 + (tid >> 6);
                if (wid < T * NHEADS) {
                    int t = wid / NHEADS, hd = wid % NHEADS, d = tid & 63;
                    float* kcl = kc + (long)l * MAXS * D;
                    float* vcl = vc + (long)l * MAXS * D;
                    int pos = basePos + t;
                    int i = d & 31;
                    float inv = __expf(-(float)i * (9.210340371976184f / 32.0f));
                    float ang = (float)pos * inv;
                    float cs = cosf(ang), sn = sinf(ang);

                    float q = qkvb[t * 3 * D + hd * HDIM + d];
                    float qp = __shfl_xor(q, 32, 64);
                    float qr = (d < 32) ? (q * cs - qp * sn) : (q * cs + qp * sn);

                    float k0 = qkvb[t * 3 * D + D + hd * HDIM + d];
                    float kp = __shfl_xor(k0, 32, 64);
                    float kr = (d < 32) ? (k0 * cs - kp * sn) : (k0 * cs + kp * sn);

                    float v0 = qkvb[t * 3 * D + 2 * D + hd * HDIM + d];
                    kcl[pos * D + hd * HDIM + d] = kr;
                    vcl[pos * D + hd * HDIM + d] = v0;

                    float sc[MAXS];
#pragma unroll
                    for (int s = 0; s < MAXS; ++s) {
                        if (s > pos) break;
                        float kv;
                        if (s < basePos) {
                            kv = kcl[s * D + hd * HDIM + d];
                        } else if (s == pos) {
                            kv = kr;
                        } else {
                            float kk = qkvb[(s - basePos) * 3 * D + D + hd * HDIM + d];
                            float kkp = __shfl_xor(kk, 32, 64);
                            float a2 = (float)s * inv;
                            float c2 = cosf(a2), s2 = sinf(a2);
                            kv = (d < 32) ? (kk * c2 - kkp * s2) : (kk * c2 + kkp * s2);
                        }
                        float dt = wave_reduce_sum(qr * kv);
                        sc[s] = dt * 0.125f;
                    }
                    float mx = -1e30f;
#pragma unroll
                    for (int s = 0; s < MAXS; ++s) { if (s > pos) break; mx = fmaxf(mx, sc[s]); }
                    float lsum = 0.f;
#pragma unroll
                    for (int s = 0; s < MAXS; ++s) { if (s > pos) break; sc[s] = expf(sc[s] - mx); lsum += sc[s]; }
                    float o = 0.f;
#pragma unroll
                    for (int s = 0; s < MAXS; ++s) {
                        if (s > pos) break;
                        float vv = (s < basePos) ? vcl[s * D + hd * HDIM + d]
                                                 : qkvb[(s - basePos) * 3 * D + 2 * D + hd * HDIM + d];
                        o += sc[s] * vv;
                    }
                    ao[t * D + hd * HDIM + d] = o / lsum;
                }
            }
            gsync(bar, bt += NB);

            // ---------- WO (+ zero qkv for next layer/step): tasks = 4 x 16 x T ----------
            {
                for (int i = bid * 256 + tid; i < T * 3 * D; i += NB * 256) qkvb[i] = 0.f;
                if (bid < 64 * T) {
                    int x = bid % 4, y = (bid / 4) % 16, t = bid / 64;
                    const float* W = p.wo + (long)l * D * D;
                    for (int i = tid; i < D; i += 256) xn[i] = ao[t * D + i];
                    __syncthreads();
                    int w = tid >> 6, lane = tid & 63;
                    int obase = x * 256;
                    int kbase = (y * 4 + w) * 16;
                    const float* Wp = W + (long)kbase * D + obase + lane * 4;
                    float4 acc = {0.f, 0.f, 0.f, 0.f};
#pragma unroll 4
                    for (int i = 0; i < 16; ++i) {
                        float xv = xn[kbase + i];
                        float4 wv4 = *(const float4*)(Wp + (long)i * D);
                        acc.x += xv * wv4.x; acc.y += xv * wv4.y;
                        acc.z += xv * wv4.z; acc.w += xv * wv4.w;
                    }
                    part[w][lane] = acc;
                    __syncthreads();
                    const float* pp = (const float*)part;
                    float s = pp[tid] + pp[256 + tid] + pp[512 + tid] + pp[768 + tid];
                    atomicAdd(&h[t * D + obase + tid], s);
                }
            }
            gsync(bar, bt += NB);

            // ---------- FFN1: tasks = 16 x 8 x T ----------
            if (bid < 128 * T) {
                int x = bid % 16, y = (bid / 16) % 8, t = bid / 128;
                load_rms(h + t * D, p.ln2 + l * D, xn, red);
                const float* W = p.w1 + (long)l * D * FF;
                int w = tid >> 6, lane = tid & 63;
                int obase = x * 256;
                int kbase = (y * 4 + w) * 32;
                const float* Wp = W + (long)kbase * FF + obase + lane * 4;
                float4 acc = {0.f, 0.f, 0.f, 0.f};
#pragma unroll 4
                for (int i = 0; i < 32; ++i) {
                    float xv = xn[kbase + i];
                    float4 wv4 = *(const float4*)(Wp + (long)i * FF);
                    acc.x += xv * wv4.x; acc.y += xv * wv4.y;
                    acc.z += xv * wv4.z; acc.w += xv * wv4.w;
                }
                part[w][lane] = acc;
                __syncthreads();
                const float* pp = (const float*)part;
                float s = pp[tid] + pp[256 + tid] + pp[512 + tid] + pp[768 + tid];
                atomicAdd(&ub[t * FF + obase + tid], s);
            }
            gsync(bar, bt += NB);

            // ---------- FFN2: tasks = 4 x 32 x T (red[] reused as gelu'd xs[128]) ----------
            if (bid < 128 * T) {
                int x = bid % 4, y = (bid / 4) % 32, t = bid / 128;
                int kblk = y * 128;
                if (tid < 128) red[tid] = geluf(ub[t * FF + kblk + tid]);
                __syncthreads();
                const float* W = p.w2 + (long)l * FF * D;
                int w = tid >> 6, lane = tid & 63;
                int obase = x * 256;
                int kloc = w * 32;
                const float* Wp = W + (long)(kblk + kloc) * D + obase + lane * 4;
                float4 acc = {0.f, 0.f, 0.f, 0.f};
#pragma unroll 4
                for (int i = 0; i < 32; ++i) {
                    float xv = red[kloc + i];
                    float4 wv4 = *(const float4*)(Wp + (long)i * D);
                    acc.x += xv * wv4.x; acc.y += xv * wv4.y;
                    acc.z += xv * wv4.z; acc.w += xv * wv4.w;
                }
                part[w][lane] = acc;
                __syncthreads();
                const float* pp = (const float*)part;
                float s = pp[tid] + pp[256 + tid] + pp[512 + tid] + pp[768 + tid];
                atomicAdd(&h[t * D + obase + tid], s);
            }
            gsync(bar, bt += NB);
        }
    };

    // prefill (2 tokens)
    step(2, 0);

    for (int g = 0; g < NGRP; ++g) {
        // ---------- HEAD: 128 blocks x 16 rows (identical to k_head) ----------
        {
            const float* hid = h + ((g == 0) ? D : 0);
            if (bid < 128) {
                load_rms(hid, p.lnf, xn, red);
                int lane = tid & 63, w = tid >> 6;
                int rbase = bid * 16 + w * 4;
                const float* Hd = p.heads + (long)g * VOC * D;
#pragma unroll
                for (int r = 0; r < 4; ++r) {
                    const float* row = Hd + (long)(rbase + r) * D;
                    float acc = 0.f;
#pragma unroll
                    for (int it = 0; it < 4; ++it) {
                        int idx = it * 256 + lane * 4;
                        float4 a = *(const float4*)(row + idx);
                        acc += a.x * xn[idx] + a.y * xn[idx + 1]
                             + a.z * xn[idx + 2] + a.w * xn[idx + 3];
                    }
                    acc = wave_reduce_sum(acc);
                    if (lane == 0) lg[rbase + r] = acc;
                }
            }
        }
        gsync(bar, bt += NB);

        // ---------- SAMPLE: block 0 only (identical to k_sample) ----------
        if (bid == 0) {
            if (tid < 64) {
                int lane = tid;
                float v[32];
#pragma unroll
                for (int j = 0; j < 32; ++j) v[j] = lg[j * 64 + lane];
                for (int r = 0; r < TOPK; ++r) {
                    float bv = v[0];
                    int bj = 0;
#pragma unroll
                    for (int j = 1; j < 32; ++j)
                        if (v[j] > bv) { bv = v[j]; bj = j; }
                    int bidx = bj * 64 + lane;
#pragma unroll
                    for (int m = 32; m >= 1; m >>= 1) {
                        float ov = __shfl_xor(bv, m, 64);
                        int oi = __shfl_xor(bidx, m, 64);
                        if (ov > bv || (ov == bv && oi < bidx)) { bv = ov; bidx = oi; }
                    }
                    if (lane == 0) { s_topv[r] = bv; s_topi[r] = bidx; }
                    if ((bidx & 63) == lane) v[bidx >> 6] = -3.0e38f;
                }
            }
            __syncthreads();
            if (tid == 0) {
                float t = fmaxf(p.temp[0], 1e-5f);
                float m = s_topv[0] / t;
                float pr[TOPK];
                float l = 0.f;
                for (int j = 0; j < TOPK; ++j) { pr[j] = expf(s_topv[j] / t - m); l += pr[j]; }
                float u = p.unis[g];
                u = fminf(fmaxf(u, 1e-6f), 1.f - 1e-6f);
                float cdf = 0.f;
                int choice = 0;
                bool found = false;
                for (int j = 0; j < TOPK; ++j) {
                    cdf += pr[j] / l;
                    if (!found && cdf >= u) { choice = j; found = true; }
                }
                s_code = s_topi[choice];
                p.out[g] = (float)s_code;
            }
            __syncthreads();
            int code = s_code;
            const float* e = p.embeds + ((long)g * VOC + code) * D;
            for (int i = tid; i < D; i += 256) {
                float ev = e[i];
                p.out[NGRP + i] += ev;
                h[i] = ev;
            }
        }
        gsync(bar, bt += NB);

        if (g + 1 < NGRP) step(1, g + 2);
    }
}

extern "C" void kernel_launch(void* const* d_in, const int* in_sizes, int n_in,
                              void* d_out, int out_size, void* d_ws, size_t ws_size,
                              hipStream_t stream) {
    const float* talker = (const float*)d_in[0];
    const float* code0  = (const float*)d_in[1];
    const float* temp   = (const float*)d_in[2];
    const float* unis   = (const float*)d_in[3];
    const float* heads  = (const float*)d_in[4];
    const float* embeds = (const float*)d_in[5];
    const float* ln1    = (const float*)d_in[6];
    const float* ln2    = (const float*)d_in[7];
    const float* lnf    = (const float*)d_in[8];
    const float* wq     = (const float*)d_in[9];
    const float* wk     = (const float*)d_in[10];
    const float* wv     = (const float*)d_in[11];
    const float* wo     = (const float*)d_in[12];
    const float* w1     = (const float*)d_in[13];
    const float* w2     = (const float*)d_in[14];
    float* out = (float*)d_out;

    float* ws   = (float*)d_ws;
    float* h    = ws;
    float* qkvb = ws + 2048;
    unsigned* bar = (unsigned*)(ws + 86016);

    k_pre<<<8, 256, 0, stream>>>(talker, code0, h, out, qkvb, bar);

    Params pr{talker, code0, temp, unis, heads, embeds, ln1, ln2, lnf,
              wq, wk, wv, wo, w1, w2, out, ws};
    // 256 blocks x 256 threads: capacity is >= 8 blocks/CU on 256 CUs, so all
    // blocks are co-resident and the device-side grid barrier cannot deadlock.
    k_all<<<dim3(NB), dim3(256), 0, stream>>>(pr);
}

// Round 2
// 2391.182 us; speedup vs baseline: 1.9293x; 1.9293x over previous
//
#include <hip/hip_runtime.h>
#include <math.h>

#define D      1024
#define NHEADS 16
#define HDIM   64
#define NL     2
#define FF     4096
#define NGRP   15
#define VOC    2048
#define TOPK   50
#define MAXS   16
#define NB     256
#define SLOT   16   // u32 spacing between barrier slots = 64B (one cacheline)

struct Params {
    const float* talker; const float* code0; const float* temp; const float* unis;
    const float* heads;  const float* embeds;
    const float* ln1; const float* ln2; const float* lnf;
    const float* wq; const float* wk; const float* wv; const float* wo;
    const float* w1; const float* w2;
    float* out; float* ws;
};

// Coherent-point scalar access for cross-block mutable buffers. These bypass the
// non-coherent per-XCD caches, so NO cache-maintenance fences (wbl2/inv) are
// needed at barriers and the (read-only, normally-loaded) weights stay in L2.
__device__ __forceinline__ float cload(const float* p) {
    return __hip_atomic_load(p, __ATOMIC_RELAXED, __HIP_MEMORY_SCOPE_AGENT);
}
__device__ __forceinline__ void cstore(float* p, float v) {
    __hip_atomic_store(p, v, __ATOMIC_RELAXED, __HIP_MEMORY_SCOPE_AGENT);
}

__device__ __forceinline__ float wave_reduce_sum(float v) {
#pragma unroll
    for (int m = 32; m >= 1; m >>= 1) v += __shfl_xor(v, m, 64);
    return v;
}

__device__ __forceinline__ float geluf(float y) {
    return 0.5f * y * (1.f + tanhf(0.7978845608028654f * (y + 0.044715f * y * y * y)));
}

// Contention-free two-level grid barrier.
// Arrival: block b relaxed-stores epoch to arrive[b*SLOT] (its own cacheline).
// Detection: block 0's 256 threads each poll ONE arrive slot.
// Release: block 0's 256 threads each store epoch to release[b*SLOT];
//          block b polls only its own release line. No RMW, no shared-line spin.
// Data visibility needs no fence: all cross-block data ops are coherence-point
// ops (cload/cstore/atomicAdd); s_waitcnt vmcnt(0) before arrival orders them.
__device__ __forceinline__ void gsync(unsigned* arrive, unsigned* release, unsigned ep) {
    __syncthreads();
    const int bid = blockIdx.x, tid = threadIdx.x;
    if (tid == 0) {
        asm volatile("s_waitcnt vmcnt(0) lgkmcnt(0)" ::: "memory");
        __hip_atomic_store(&arrive[bid * SLOT], ep, __ATOMIC_RELAXED, __HIP_MEMORY_SCOPE_AGENT);
    }
    if (bid == 0) {
        while (__hip_atomic_load(&arrive[tid * SLOT], __ATOMIC_RELAXED,
                                 __HIP_MEMORY_SCOPE_AGENT) < ep)
            __builtin_amdgcn_s_sleep(4);
        __syncthreads();
        __hip_atomic_store(&release[tid * SLOT], ep, __ATOMIC_RELAXED, __HIP_MEMORY_SCOPE_AGENT);
    } else if (tid == 0) {
        while (__hip_atomic_load(&release[bid * SLOT], __ATOMIC_RELAXED,
                                 __HIP_MEMORY_SCOPE_AGENT) < ep)
            __builtin_amdgcn_s_sleep(4);
    }
    asm volatile("" ::: "memory");
    __syncthreads();
}

// xn[] = rms(coherent-load src)*w, red[] is 256-float scratch.
__device__ __forceinline__ void load_rms(const float* __restrict__ src,
                                         const float* __restrict__ w,
                                         float* xn, float* red) {
    int tid = threadIdx.x;
    float ss = 0.f;
    for (int i = tid; i < D; i += 256) { float v = cload(src + i); xn[i] = v; ss += v * v; }
    red[tid] = ss;
    __syncthreads();
    for (int s = 128; s > 0; s >>= 1) {
        if (tid < s) red[tid] += red[tid + s];
        __syncthreads();
    }
    float inv = rsqrtf(red[0] / (float)D + 1e-6f);
    for (int i = tid; i < D; i += 256) xn[i] = xn[i] * inv * w[i];
    __syncthreads();
}

// init: h = talker||code0, out tail = code0, zero qkv + barrier slots.
__global__ __launch_bounds__(256) void k_pre(const float* __restrict__ th,
                                             const float* __restrict__ c0,
                                             float* __restrict__ h,
                                             float* __restrict__ out,
                                             float* __restrict__ qkv,
                                             unsigned* __restrict__ slots) {
    int i = blockIdx.x * 256 + threadIdx.x;   // grid 8 x 256 = 2048
    if (i < 1024) {
        h[i] = th[i];
        h[D + i] = c0[i];
        out[NGRP + i] = c0[i];
    }
    for (int j = i; j < 2 * 3 * D; j += 2048) qkv[j] = 0.f;
    for (int j = i; j < 2 * NB * SLOT; j += 2048) slots[j] = 0u;
}

__global__ __launch_bounds__(256) void k_all(Params p) {
    __shared__ float xn[D];
    __shared__ float red[256];
    __shared__ float4 part[4][64];
    __shared__ float s_topv[TOPK];
    __shared__ int   s_topi[TOPK];
    __shared__ int   s_code;

    float* ws   = p.ws;
    float* h    = ws;            // 2*1024
    float* qkvb = ws + 2048;     // 2*3*1024
    float* ao   = ws + 8192;     // 2*1024
    float* kc   = ws + 10240;    // 2*16*1024
    float* vc   = ws + 43008;    // 2*16*1024
    float* ub   = ws + 75776;    // 2*4096
    float* lg   = ws + 83968;    // 2048
    unsigned* arrive  = (unsigned*)(ws + 86016);  // NB*SLOT u32
    unsigned* release = arrive + NB * SLOT;       // NB*SLOT u32

    const int bid = blockIdx.x;
    const int tid = threadIdx.x;
    unsigned ep = 0;

    auto GS = [&]() { gsync(arrive, release, ++ep); };

    auto step = [&](int T, int basePos) {
        for (int l = 0; l < NL; ++l) {
            // ---------- QKV: tasks = 12 x 8 x T ----------
            if (bid < 96 * T) {
                int x = bid % 12, y = (bid / 12) % 8, t = bid / 96;
                int m = x >> 2, ob = x & 3;
                load_rms(h + t * D, p.ln1 + l * D, xn, red);
                const float* W = ((m == 0) ? p.wq : (m == 1) ? p.wk : p.wv) + (long)l * D * D;
                int w = tid >> 6, lane = tid & 63;
                int obase = ob * 256;
                int kbase = (y * 4 + w) * 32;
                const float* Wp = W + (long)kbase * D + obase + lane * 4;
                float4 acc = {0.f, 0.f, 0.f, 0.f};
#pragma unroll 4
                for (int i = 0; i < 32; ++i) {
                    float xv = xn[kbase + i];
                    float4 wv4 = *(const float4*)(Wp + (long)i * D);
                    acc.x += xv * wv4.x; acc.y += xv * wv4.y;
                    acc.z += xv * wv4.z; acc.w += xv * wv4.w;
                }
                part[w][lane] = acc;
                __syncthreads();
                const float* pp = (const float*)part;
                float s = pp[tid] + pp[256 + tid] + pp[512 + tid] + pp[768 + tid];
                atomicAdd(&qkvb[t * 3 * D + m * D + obase + tid], s);
            }
            GS();

            // ---------- ATTN (+ zero ub): wave tasks = T x 16 ----------
            {
                for (int i = bid * 256 + tid; i < T * FF; i += NB * 256) cstore(&ub[i], 0.f);
                int wid = bid * 4 + (tid >> 6);
                if (wid < T * NHEADS) {
                    int t = wid / NHEADS, hd = wid % NHEADS, d = tid & 63;
                    float* kcl = kc + (long)l * MAXS * D;
                    float* vcl = vc + (long)l * MAXS * D;
                    int pos = basePos + t;
                    int i = d & 31;
                    float inv = __expf(-(float)i * (9.210340371976184f / 32.0f));
                    float ang = (float)pos * inv;
                    float cs = cosf(ang), sn = sinf(ang);

                    float q = cload(&qkvb[t * 3 * D + hd * HDIM + d]);
                    float qp = __shfl_xor(q, 32, 64);
                    float qr = (d < 32) ? (q * cs - qp * sn) : (q * cs + qp * sn);

                    float k0 = cload(&qkvb[t * 3 * D + D + hd * HDIM + d]);
                    float kp = __shfl_xor(k0, 32, 64);
                    float kr = (d < 32) ? (k0 * cs - kp * sn) : (k0 * cs + kp * sn);

                    float v0 = cload(&qkvb[t * 3 * D + 2 * D + hd * HDIM + d]);
                    cstore(&kcl[pos * D + hd * HDIM + d], kr);
                    cstore(&vcl[pos * D + hd * HDIM + d], v0);

                    float sc[MAXS];
#pragma unroll
                    for (int s = 0; s < MAXS; ++s) {
                        if (s > pos) break;
                        float kv;
                        if (s < basePos) {
                            kv = cload(&kcl[s * D + hd * HDIM + d]);
                        } else if (s == pos) {
                            kv = kr;
                        } else {
                            float kk = cload(&qkvb[(s - basePos) * 3 * D + D + hd * HDIM + d]);
                            float kkp = __shfl_xor(kk, 32, 64);
                            float a2 = (float)s * inv;
                            float c2 = cosf(a2), s2 = sinf(a2);
                            kv = (d < 32) ? (kk * c2 - kkp * s2) : (kk * c2 + kkp * s2);
                        }
                        float dt = wave_reduce_sum(qr * kv);
                        sc[s] = dt * 0.125f;
                    }
                    float mx = -1e30f;
#pragma unroll
                    for (int s = 0; s < MAXS; ++s) { if (s > pos) break; mx = fmaxf(mx, sc[s]); }
                    float lsum = 0.f;
#pragma unroll
                    for (int s = 0; s < MAXS; ++s) { if (s > pos) break; sc[s] = expf(sc[s] - mx); lsum += sc[s]; }
                    float o = 0.f;
#pragma unroll
                    for (int s = 0; s < MAXS; ++s) {
                        if (s > pos) break;
                        float vv = (s < basePos) ? cload(&vcl[s * D + hd * HDIM + d])
                                                 : cload(&qkvb[(s - basePos) * 3 * D + 2 * D + hd * HDIM + d]);
                        o += sc[s] * vv;
                    }
                    cstore(&ao[t * D + hd * HDIM + d], o / lsum);
                }
            }
            GS();

            // ---------- WO (+ zero qkv for next layer/step): tasks = 4 x 16 x T ----------
            {
                for (int i = bid * 256 + tid; i < T * 3 * D; i += NB * 256) cstore(&qkvb[i], 0.f);
                if (bid < 64 * T) {
                    int x = bid % 4, y = (bid / 4) % 16, t = bid / 64;
                    const float* W = p.wo + (long)l * D * D;
                    for (int i = tid; i < D; i += 256) xn[i] = cload(&ao[t * D + i]);
                    __syncthreads();
                    int w = tid >> 6, lane = tid & 63;
                    int obase = x * 256;
                    int kbase = (y * 4 + w) * 16;
                    const float* Wp = W + (long)kbase * D + obase + lane * 4;
                    float4 acc = {0.f, 0.f, 0.f, 0.f};
#pragma unroll 4
                    for (int i = 0; i < 16; ++i) {
                        float xv = xn[kbase + i];
                        float4 wv4 = *(const float4*)(Wp + (long)i * D);
                        acc.x += xv * wv4.x; acc.y += xv * wv4.y;
                        acc.z += xv * wv4.z; acc.w += xv * wv4.w;
                    }
                    part[w][lane] = acc;
                    __syncthreads();
                    const float* pp = (const float*)part;
                    float s = pp[tid] + pp[256 + tid] + pp[512 + tid] + pp[768 + tid];
                    atomicAdd(&h[t * D + obase + tid], s);
                }
            }
            GS();

            // ---------- FFN1: tasks = 16 x 8 x T ----------
            if (bid < 128 * T) {
                int x = bid % 16, y = (bid / 16) % 8, t = bid / 128;
                load_rms(h + t * D, p.ln2 + l * D, xn, red);
                const float* W = p.w1 + (long)l * D * FF;
                int w = tid >> 6, lane = tid & 63;
                int obase = x * 256;
                int kbase = (y * 4 + w) * 32;
                const float* Wp = W + (long)kbase * FF + obase + lane * 4;
                float4 acc = {0.f, 0.f, 0.f, 0.f};
#pragma unroll 4
                for (int i = 0; i < 32; ++i) {
                    float xv = xn[kbase + i];
                    float4 wv4 = *(const float4*)(Wp + (long)i * FF);
                    acc.x += xv * wv4.x; acc.y += xv * wv4.y;
                    acc.z += xv * wv4.z; acc.w += xv * wv4.w;
                }
                part[w][lane] = acc;
                __syncthreads();
                const float* pp = (const float*)part;
                float s = pp[tid] + pp[256 + tid] + pp[512 + tid] + pp[768 + tid];
                atomicAdd(&ub[t * FF + obase + tid], s);
            }
            GS();

            // ---------- FFN2: tasks = 4 x 32 x T (red[] reused as gelu'd xs[128]) ----------
            if (bid < 128 * T) {
                int x = bid % 4, y = (bid / 4) % 32, t = bid / 128;
                int kblk = y * 128;
                if (tid < 128) red[tid] = geluf(cload(&ub[t * FF + kblk + tid]));
                __syncthreads();
                const float* W = p.w2 + (long)l * FF * D;
                int w = tid >> 6, lane = tid & 63;
                int obase = x * 256;
                int kloc = w * 32;
                const float* Wp = W + (long)(kblk + kloc) * D + obase + lane * 4;
                float4 acc = {0.f, 0.f, 0.f, 0.f};
#pragma unroll 4
                for (int i = 0; i < 32; ++i) {
                    float xv = red[kloc + i];
                    float4 wv4 = *(const float4*)(Wp + (long)i * D);
                    acc.x += xv * wv4.x; acc.y += xv * wv4.y;
                    acc.z += xv * wv4.z; acc.w += xv * wv4.w;
                }
                part[w][lane] = acc;
                __syncthreads();
                const float* pp = (const float*)part;
                float s = pp[tid] + pp[256 + tid] + pp[512 + tid] + pp[768 + tid];
                atomicAdd(&h[t * D + obase + tid], s);
            }
            GS();
        }
    };

    // prefill (2 tokens)
    step(2, 0);

    for (int g = 0; g < NGRP; ++g) {
        // ---------- HEAD: 128 blocks x 16 rows ----------
        {
            const float* hid = h + ((g == 0) ? D : 0);
            if (bid < 128) {
                load_rms(hid, p.lnf, xn, red);
                int lane = tid & 63, w = tid >> 6;
                int rbase = bid * 16 + w * 4;
                const float* Hd = p.heads + (long)g * VOC * D;
#pragma unroll
                for (int r = 0; r < 4; ++r) {
                    const float* row = Hd + (long)(rbase + r) * D;
                    float acc = 0.f;
#pragma unroll
                    for (int it = 0; it < 4; ++it) {
                        int idx = it * 256 + lane * 4;
                        float4 a = *(const float4*)(row + idx);
                        acc += a.x * xn[idx] + a.y * xn[idx + 1]
                             + a.z * xn[idx + 2] + a.w * xn[idx + 3];
                    }
                    acc = wave_reduce_sum(acc);
                    if (lane == 0) cstore(&lg[rbase + r], acc);
                }
            }
        }
        GS();

        // ---------- SAMPLE: block 0 only ----------
        if (bid == 0) {
            if (tid < 64) {
                int lane = tid;
                float v[32];
#pragma unroll
                for (int j = 0; j < 32; ++j) v[j] = cload(&lg[j * 64 + lane]);
                for (int r = 0; r < TOPK; ++r) {
                    float bv = v[0];
                    int bj = 0;
#pragma unroll
                    for (int j = 1; j < 32; ++j)
                        if (v[j] > bv) { bv = v[j]; bj = j; }
                    int bidx = bj * 64 + lane;
#pragma unroll
                    for (int m = 32; m >= 1; m >>= 1) {
                        float ov = __shfl_xor(bv, m, 64);
                        int oi = __shfl_xor(bidx, m, 64);
                        if (ov > bv || (ov == bv && oi < bidx)) { bv = ov; bidx = oi; }
                    }
                    if (lane == 0) { s_topv[r] = bv; s_topi[r] = bidx; }
                    if ((bidx & 63) == lane) v[bidx >> 6] = -3.0e38f;
                }
            }
            __syncthreads();
            if (tid == 0) {
                float t = fmaxf(p.temp[0], 1e-5f);
                float m = s_topv[0] / t;
                float pr[TOPK];
                float l = 0.f;
                for (int j = 0; j < TOPK; ++j) { pr[j] = expf(s_topv[j] / t - m); l += pr[j]; }
                float u = p.unis[g];
                u = fminf(fmaxf(u, 1e-6f), 1.f - 1e-6f);
                float cdf = 0.f;
                int choice = 0;
                bool found = false;
                for (int j = 0; j < TOPK; ++j) {
                    cdf += pr[j] / l;
                    if (!found && cdf >= u) { choice = j; found = true; }
                }
                s_code = s_topi[choice];
                p.out[g] = (float)s_code;
            }
            __syncthreads();
            int code = s_code;
            const float* e = p.embeds + ((long)g * VOC + code) * D;
            for (int i = tid; i < D; i += 256) {
                float ev = e[i];
                p.out[NGRP + i] += ev;
                cstore(&h[i], ev);
            }
        }
        GS();

        if (g + 1 < NGRP) step(1, g + 2);
    }
}

extern "C" void kernel_launch(void* const* d_in, const int* in_sizes, int n_in,
                              void* d_out, int out_size, void* d_ws, size_t ws_size,
                              hipStream_t stream) {
    const float* talker = (const float*)d_in[0];
    const float* code0  = (const float*)d_in[1];
    const float* temp   = (const float*)d_in[2];
    const float* unis   = (const float*)d_in[3];
    const float* heads  = (const float*)d_in[4];
    const float* embeds = (const float*)d_in[5];
    const float* ln1    = (const float*)d_in[6];
    const float* ln2    = (const float*)d_in[7];
    const float* lnf    = (const float*)d_in[8];
    const float* wq     = (const float*)d_in[9];
    const float* wk     = (const float*)d_in[10];
    const float* wv     = (const float*)d_in[11];
    const float* wo     = (const float*)d_in[12];
    const float* w1     = (const float*)d_in[13];
    const float* w2     = (const float*)d_in[14];
    float* out = (float*)d_out;

    float* ws   = (float*)d_ws;
    float* h    = ws;
    float* qkvb = ws + 2048;
    unsigned* slots = (unsigned*)(ws + 86016);

    k_pre<<<8, 256, 0, stream>>>(talker, code0, h, out, qkvb, slots);

    Params pr{talker, code0, temp, unis, heads, embeds, ln1, ln2, lnf,
              wq, wk, wv, wo, w1, w2, out, ws};
    // 256 blocks x 256 threads: >= 4 blocks/CU capacity on 256 CUs, so all
    // blocks are co-resident and the device-side grid barrier cannot deadlock.
    k_all<<<dim3(NB), dim3(256), 0, stream>>>(pr);
}